// Round 23
// baseline (33.910 us; speedup 1.0000x reference)
//
#include <hip/hip_runtime.h>

#define SENT    256
#define BATCH   64
#define WLEN    16
#define D_WORDE 300
#define D_CHARE 50
#define OUT_CH  200
#define KSIZE   3
#define NPOS    14
#define D_OUT   500
#define NWORDS  (SENT * BATCH)

// GEMM geometry (transposed): per position p, M=16 words, N=13x16=208, K=192.
// A[word][kg=kk*64+c] = emb[word][p+kk][c]; 3-row sliding window over p.
// Bias folded into K: charP col63 = 1.0, WO[o][191] = conv_b[o].
#define KPAD      192
#define MPAD      208
#define CHARP_U16 (129 * 64)
#define WO_U16    (MPAD * KPAD)
#define WS_NEED   ((size_t)(CHARP_U16 + WO_U16) * 2)

#define WPB         16                 // words per block (= M of each p-GEMM)
#define TILE_U16    (WPB * 1024)       // 32 KB staging tile
#define CBUF_STRIDE 256                // padded col stride for conv-out LDS buffer
#define CONV_BLOCKS (NWORDS / WPB)     // 1024 blocks x 512 threads

typedef short  short8  __attribute__((ext_vector_type(8)));
typedef ushort ushort8 __attribute__((ext_vector_type(8)));
typedef float  float4v __attribute__((ext_vector_type(4)));

#define GLOAD16(SRC, DST)                                                     \
    __builtin_amdgcn_global_load_lds(                                         \
        (const __attribute__((address_space(1))) void*)(SRC),                 \
        (__attribute__((address_space(3))) void*)(DST), 16, 0, 0)

__device__ __forceinline__ ushort f2bf(float f) {
    unsigned u = __float_as_uint(f);
    u = (u + 0x7FFFu + ((u >> 16) & 1u)) >> 16;   // RNE
    return (ushort)u;
}

// ---------- prep: bf16 char table (col63=1.0) + K-major weights (kg191=bias) ----------
__global__ void prep_kernel(const float* __restrict__ W_char,
                            const float* __restrict__ conv_w,
                            const float* __restrict__ conv_b,
                            ushort* __restrict__ ws) {
    int j = blockIdx.x * 256 + threadIdx.x;
    if (j < CHARP_U16) {
        int r = j >> 6, c = j & 63;
        ushort v = 0;
        if (r < 128) {
            if (c < D_CHARE)      v = f2bf(W_char[r * D_CHARE + c]);
            else if (c == 63)     v = 0x3F80;        // 1.0 bf16 (bias lane)
        }
        ws[j] = v;
    }
    int j2 = j - CHARP_U16;
    if (j2 >= 0 && j2 < WO_U16) {
        int o = j2 / KPAD, kg = j2 - o * KPAD;
        int kk = kg >> 6, c = kg & 63;
        float v = 0.f;
        if (o < OUT_CH) {
            if (c < D_CHARE)      v = conv_w[o * (D_CHARE * KSIZE) + c * KSIZE + kk];
            else if (kg == 191)   v = conv_b[o];     // bias rides K-slot 191
        }
        ws[CHARP_U16 + j2] = f2bf(v);
    }
}

__device__ __forceinline__ float4v fmax4(float4v a, float4v b) {
    float4v r;
    r[0] = fmaxf(a[0], b[0]); r[1] = fmaxf(a[1], b[1]);
    r[2] = fmaxf(a[2], b[2]); r[3] = fmaxf(a[3], b[3]);
    return r;
}

// A-frag read: word l15, LDS row `row`, true granule g (0..7); swizzle ^(row&7)^(word&7)
__device__ __forceinline__ short8 lda(const ushort* __restrict__ tile,
                                      int l15, int row, int g) {
    int pos = g ^ (row & 7) ^ (l15 & 7);
    return *(const short8*)&tile[l15 * 1024 + row * 64 + (pos << 3)];
}

// NT tiles {tbase..}; 14-position sliding-window GEMM, in-register max, cbuf store.
template <int NT>
__device__ __forceinline__ void conv_ploop(int tbase, int lane, int l15, int lg,
                                           const ushort* __restrict__ tile,
                                           const ushort* __restrict__ WO,
                                           float* __restrict__ cbuf) {
    short8 B[NT][6];
    #pragma unroll
    for (int i = 0; i < NT; i++) {
        int col = (tbase + i) * 16 + l15;                 // <= 207 < MPAD
        #pragma unroll
        for (int s = 0; s < 6; s++)
            B[i][s] = *(const short8*)&WO[col * KPAD + s * 32 + lg * 8];
    }

    // window rows p, p+1, p+2 (two k-halves each)
    short8 a0 = lda(tile, l15, 0, lg),     a1 = lda(tile, l15, 0, 4 + lg);
    short8 a2 = lda(tile, l15, 1, lg),     a3 = lda(tile, l15, 1, 4 + lg);
    short8 a4 = lda(tile, l15, 2, lg),     a5 = lda(tile, l15, 2, 4 + lg);

    float4v mx[NT];
    #pragma unroll
    for (int p = 0; p < NPOS; p++) {
        float4v acc[NT];
        #pragma unroll
        for (int i = 0; i < NT; i++) acc[i] = (float4v){0, 0, 0, 0};
        #pragma unroll
        for (int i = 0; i < NT; i++) acc[i] = __builtin_amdgcn_mfma_f32_16x16x32_bf16(a0, B[i][0], acc[i], 0, 0, 0);
        #pragma unroll
        for (int i = 0; i < NT; i++) acc[i] = __builtin_amdgcn_mfma_f32_16x16x32_bf16(a1, B[i][1], acc[i], 0, 0, 0);
        #pragma unroll
        for (int i = 0; i < NT; i++) acc[i] = __builtin_amdgcn_mfma_f32_16x16x32_bf16(a2, B[i][2], acc[i], 0, 0, 0);
        #pragma unroll
        for (int i = 0; i < NT; i++) acc[i] = __builtin_amdgcn_mfma_f32_16x16x32_bf16(a3, B[i][3], acc[i], 0, 0, 0);
        #pragma unroll
        for (int i = 0; i < NT; i++) acc[i] = __builtin_amdgcn_mfma_f32_16x16x32_bf16(a4, B[i][4], acc[i], 0, 0, 0);
        #pragma unroll
        for (int i = 0; i < NT; i++) acc[i] = __builtin_amdgcn_mfma_f32_16x16x32_bf16(a5, B[i][5], acc[i], 0, 0, 0);

        #pragma unroll
        for (int i = 0; i < NT; i++) mx[i] = (p == 0) ? acc[i] : fmax4(mx[i], acc[i]);

        if (p < NPOS - 1) {          // slide window to rows p+1..p+3
            a0 = a2; a1 = a3; a2 = a4; a3 = a5;
            a4 = lda(tile, l15, p + 3, lg);
            a5 = lda(tile, l15, p + 3, 4 + lg);
        }
    }

    // store to LDS cbuf (C row = word = lg*4 + j, verified layout); no col mask
    // (tile12's cols 200..207 land in pad, never read back)
    #pragma unroll
    for (int i = 0; i < NT; i++) {
        int col = (tbase + i) * 16 + l15;
        #pragma unroll
        for (int j = 0; j < 4; j++)
            cbuf[(lg * 4 + j) * CBUF_STRIDE + col] = mx[i][j];
    }
}

// emb rows [r0, r0+cnt): 4-in-flight issue/store (proven r16/r18 pattern)
__device__ __forceinline__ void emb_rows(int block0, int r0, int cnt, int lane,
                                         const int* __restrict__ words,
                                         const float* __restrict__ W_word,
                                         float* __restrict__ out) {
    const bool tail = lane < (75 - 64);
    #pragma unroll 1
    for (int r4 = 0; r4 < cnt; r4 += 4) {
        const int m0 = block0 + r0 + r4;
        float4v e0[4], e1[4];
        #pragma unroll
        for (int j = 0; j < 4; j++) {
            const float4v* __restrict__ src =
                (const float4v*)(W_word + (size_t)words[m0 + j] * D_WORDE);
            e0[j] = src[lane];
            e1[j] = tail ? src[64 + lane] : (float4v){0, 0, 0, 0};
        }
        #pragma unroll
        for (int j = 0; j < 4; j++) {
            float4v* __restrict__ dst = (float4v*)(out + (size_t)(m0 + j) * D_OUT);
            dst[lane] = e0[j];
            if (tail) dst[64 + lane] = e1[j];
        }
    }
}

// ---------- uniform 512-thread block ----------
// stage | bar | {6x tile-pair, tile12+4emb, 12emb} | bar | coalesced conv store
__global__ void __launch_bounds__(512)
fused_kernel(const int* __restrict__ words, const int* __restrict__ chars,
             const float* __restrict__ W_word, const ushort* __restrict__ ws,
             float* __restrict__ out) {
    __shared__ __align__(16) ushort tile[TILE_U16];              // 32 KB
    __shared__ __align__(16) float  cbuf[WPB * CBUF_STRIDE];     // 16 KB

    const int tid  = threadIdx.x;
    const int lane = tid & 63;
    const int wave = tid >> 6;          // 0..7
    const int l15  = lane & 15;
    const int lg   = lane >> 4;

    const ushort* __restrict__ charP = ws;
    const ushort* __restrict__ WO    = ws + CHARP_U16;
    const int block0 = blockIdx.x * WPB;

    // ---- stage: every wave stages words {2w, 2w+1}; linear dest, swizzled source
    #pragma unroll
    for (int ww = 0; ww < 2; ww++) {
        const int wl = wave * 2 + ww;
        const int m  = block0 + wl;
        const int* __restrict__ cbase = chars + ((m & 63) * SENT + (m >> 6)) * WLEN;
        const int srcg = (lane & 7) ^ ((lane >> 3) & 7) ^ (wl & 7);
        #pragma unroll
        for (int s = 0; s < 2; s++) {
            const int idv = cbase[s * 8 + (lane >> 3)];
            GLOAD16(charP + idv * 64 + (srcg << 3), &tile[wl * 1024 + s * 512]);
        }
    }
    __syncthreads();

    if (wave < 6) {
        conv_ploop<2>(2 * wave, lane, l15, lg, tile, WO, cbuf);   // tiles 0..11
    } else if (wave == 6) {
        conv_ploop<1>(12, lane, l15, lg, tile, WO, cbuf);         // tile 12
        emb_rows(block0, 12, 4, lane, words, W_word, out);        // + 4 emb rows
    } else {
        emb_rows(block0, 0, 12, lane, words, W_word, out);        // 12 emb rows
    }
    __syncthreads();

    // ---- cooperative coalesced conv store: wave stores rows {2w, 2w+1}
    #pragma unroll
    for (int rr = 0; rr < 2; rr++) {
        const int r = wave * 2 + rr;
        const float* __restrict__ src = &cbuf[r * CBUF_STRIDE];
        float* __restrict__ dst = out + (size_t)(block0 + r) * D_OUT + D_WORDE;
        dst[lane]       = src[lane];
        dst[64 + lane]  = src[64 + lane];
        dst[128 + lane] = src[128 + lane];
        if (lane < 8) dst[192 + lane] = src[192 + lane];
    }
}

// ---------- fallbacks (tiny ws): round-1 proven kernels ----------
__global__ void __launch_bounds__(256)
word_emb_kernel(const int* __restrict__ words, const float* __restrict__ W_word,
                float* __restrict__ out) {
    int wave = threadIdx.x >> 6, lane = threadIdx.x & 63;
    int m = blockIdx.x * 4 + wave;
    int idx = words[m];
    const float* __restrict__ src = W_word + (size_t)idx * D_WORDE;
    float* __restrict__ dst = out + (size_t)m * D_OUT;
    for (int j = lane; j < D_WORDE; j += 64) dst[j] = src[j];
}

__global__ void __launch_bounds__(256)
char_conv_f32_kernel(const int* __restrict__ chars, const float* __restrict__ W_char,
                     const float* __restrict__ conv_w, const float* __restrict__ conv_b,
                     float* __restrict__ out) {
    __shared__ __align__(16) float xs[D_CHARE * WLEN];
    __shared__ int ids[WLEN];
    int m = blockIdx.x, s = m >> 6, b = m & 63, tid = threadIdx.x;
    if (tid < WLEN) ids[tid] = chars[(b * SENT + s) * WLEN + tid];
    __syncthreads();
    for (int e = tid; e < D_CHARE * WLEN; e += 256) {
        int c = e >> 4, l = e & 15;
        xs[e] = W_char[ids[l] * D_CHARE + c];
    }
    __syncthreads();
    if (tid < OUT_CH) {
        float acc[NPOS];
        #pragma unroll
        for (int p = 0; p < NPOS; p++) acc[p] = 0.f;
        const float4* xs4 = (const float4*)xs;
        for (int c = 0; c < D_CHARE; c++) {
            float4 a0 = xs4[c*4+0], a1 = xs4[c*4+1], a2 = xs4[c*4+2], a3 = xs4[c*4+3];
            float xr[WLEN] = {a0.x,a0.y,a0.z,a0.w, a1.x,a1.y,a1.z,a1.w,
                              a2.x,a2.y,a2.z,a2.w, a3.x,a3.y,a3.z,a3.w};
            #pragma unroll
            for (int k = 0; k < KSIZE; k++) {
                float wv = conv_w[tid * (D_CHARE * KSIZE) + c * KSIZE + k];
                #pragma unroll
                for (int p = 0; p < NPOS; p++) acc[p] = fmaf(wv, xr[p + k], acc[p]);
            }
        }
        float mx = acc[0];
        #pragma unroll
        for (int p = 1; p < NPOS; p++) mx = fmaxf(mx, acc[p]);
        out[(size_t)m * D_OUT + D_WORDE + tid] = mx + conv_b[tid];
    }
}

extern "C" void kernel_launch(void* const* d_in, const int* in_sizes, int n_in,
                              void* d_out, int out_size, void* d_ws, size_t ws_size,
                              hipStream_t stream) {
    const int*   words  = (const int*)d_in[0];
    const int*   chars  = (const int*)d_in[1];
    const float* W_word = (const float*)d_in[2];
    const float* W_char = (const float*)d_in[3];
    const float* conv_w = (const float*)d_in[4];
    const float* conv_b = (const float*)d_in[5];
    float* out = (float*)d_out;

    if (ws_size >= WS_NEED) {
        ushort* ws = (ushort*)d_ws;
        hipLaunchKernelGGL(prep_kernel,
                           dim3((CHARP_U16 + WO_U16 + 255) / 256), dim3(256), 0, stream,
                           W_char, conv_w, conv_b, ws);
        hipLaunchKernelGGL(fused_kernel, dim3(CONV_BLOCKS), dim3(512), 0, stream,
                           words, chars, W_word, ws, out);
    } else {
        hipLaunchKernelGGL(word_emb_kernel, dim3(NWORDS / 4), dim3(256), 0, stream,
                           words, W_word, out);
        hipLaunchKernelGGL(char_conv_f32_kernel, dim3(NWORDS), dim3(256), 0, stream,
                           chars, W_char, conv_w, conv_b, out);
    }
}

// Round 24
// 32.897 us; speedup vs baseline: 1.0308x; 1.0308x over previous
//
#include <hip/hip_runtime.h>

#define SENT    256
#define BATCH   64
#define WLEN    16
#define D_WORDE 300
#define D_CHARE 50
#define OUT_CH  200
#define KSIZE   3
#define NPOS    14
#define D_OUT   500
#define NWORDS  (SENT * BATCH)

// GEMM geometry (transposed): per position p, M=16 words, N=13x16=208, K=192.
// A[word][kg=kk*64+c] = emb[word][p+kk][c]; 4-row sliding window, p-PAIR ILP.
// Bias folded into K: charP col63 = 1.0, WO[o][191] = conv_b[o].
#define KPAD      192
#define MPAD      208
#define CHARP_U16 (129 * 64)
#define WO_U16    (MPAD * KPAD)
#define WS_NEED   ((size_t)(CHARP_U16 + WO_U16) * 2)

#define WPB         16                 // words per block (= M of each p-GEMM)
#define TILE_U16    (WPB * 1024)       // 32 KB staging tile
#define CONV_BLOCKS (NWORDS / WPB)     // 1024 blocks x 512 threads

typedef short  short8  __attribute__((ext_vector_type(8)));
typedef ushort ushort8 __attribute__((ext_vector_type(8)));
typedef float  float4v __attribute__((ext_vector_type(4)));

#define GLOAD16(SRC, DST)                                                     \
    __builtin_amdgcn_global_load_lds(                                         \
        (const __attribute__((address_space(1))) void*)(SRC),                 \
        (__attribute__((address_space(3))) void*)(DST), 16, 0, 0)

__device__ __forceinline__ ushort f2bf(float f) {
    unsigned u = __float_as_uint(f);
    u = (u + 0x7FFFu + ((u >> 16) & 1u)) >> 16;   // RNE
    return (ushort)u;
}

// ---------- prep: bf16 char table (col63=1.0) + K-major weights (kg191=bias) ----------
__global__ void prep_kernel(const float* __restrict__ W_char,
                            const float* __restrict__ conv_w,
                            const float* __restrict__ conv_b,
                            ushort* __restrict__ ws) {
    int j = blockIdx.x * 256 + threadIdx.x;
    if (j < CHARP_U16) {
        int r = j >> 6, c = j & 63;
        ushort v = 0;
        if (r < 128) {
            if (c < D_CHARE)      v = f2bf(W_char[r * D_CHARE + c]);
            else if (c == 63)     v = 0x3F80;        // 1.0 bf16 (bias lane)
        }
        ws[j] = v;
    }
    int j2 = j - CHARP_U16;
    if (j2 >= 0 && j2 < WO_U16) {
        int o = j2 / KPAD, kg = j2 - o * KPAD;
        int kk = kg >> 6, c = kg & 63;
        float v = 0.f;
        if (o < OUT_CH) {
            if (c < D_CHARE)      v = conv_w[o * (D_CHARE * KSIZE) + c * KSIZE + kk];
            else if (kg == 191)   v = conv_b[o];     // bias rides K-slot 191
        }
        ws[CHARP_U16 + j2] = f2bf(v);
    }
}

__device__ __forceinline__ float4v fmax4(float4v a, float4v b) {
    float4v r;
    r[0] = fmaxf(a[0], b[0]); r[1] = fmaxf(a[1], b[1]);
    r[2] = fmaxf(a[2], b[2]); r[3] = fmaxf(a[3], b[3]);
    return r;
}

// A-frag read: word l15, LDS row `row`, true granule g (0..7); swizzle ^(row&7)^(word&7)
__device__ __forceinline__ short8 lda(const ushort* __restrict__ tile,
                                      int l15, int row, int g) {
    int pos = g ^ (row & 7) ^ (l15 & 7);
    return *(const short8*)&tile[l15 * 1024 + row * 64 + (pos << 3)];
}

// NT tiles {tbase..}; p-PAIR sliding-window GEMM (4 indep MFMA chains), in-reg max.
// w[j]: window frag, j = rowoff*2 + half, rows p..p+3. acc_p uses w[s], acc_q w[s+2].
template <int NT>
__device__ __forceinline__ void conv_ploop(int tbase, int lane, int l15, int lg,
                                           const ushort* __restrict__ tile,
                                           const ushort* __restrict__ WO,
                                           float* __restrict__ out, int block0) {
    short8 B[NT][6];
    #pragma unroll
    for (int i = 0; i < NT; i++) {
        int col = (tbase + i) * 16 + l15;                 // <= 207 < MPAD
        #pragma unroll
        for (int s = 0; s < 6; s++)
            B[i][s] = *(const short8*)&WO[col * KPAD + s * 32 + lg * 8];
    }

    // 4-row window: rows 0..3, halves 0/1 -> w[0..7]
    short8 w[8];
    #pragma unroll
    for (int rr = 0; rr < 4; rr++) {
        w[rr * 2]     = lda(tile, l15, rr, lg);
        w[rr * 2 + 1] = lda(tile, l15, rr, 4 + lg);
    }

    float4v mx[NT];
    #pragma unroll
    for (int pp = 0; pp < 7; pp++) {                      // positions p=2pp, q=2pp+1
        float4v ap[NT], aq[NT];
        #pragma unroll
        for (int i = 0; i < NT; i++) { ap[i] = (float4v){0,0,0,0}; aq[i] = (float4v){0,0,0,0}; }
        #pragma unroll
        for (int s = 0; s < 6; s++) {
            #pragma unroll
            for (int i = 0; i < NT; i++) {
                ap[i] = __builtin_amdgcn_mfma_f32_16x16x32_bf16(w[s],     B[i][s], ap[i], 0, 0, 0);
                aq[i] = __builtin_amdgcn_mfma_f32_16x16x32_bf16(w[s + 2], B[i][s], aq[i], 0, 0, 0);
            }
        }
        #pragma unroll
        for (int i = 0; i < NT; i++) {
            float4v m2 = fmax4(ap[i], aq[i]);
            mx[i] = (pp == 0) ? m2 : fmax4(mx[i], m2);
        }
        if (pp < 6) {                                     // slide window by 2 rows
            #pragma unroll
            for (int j = 0; j < 4; j++) w[j] = w[j + 4];
            const int r0 = 2 * pp + 4;
            w[4] = lda(tile, l15, r0,     lg);
            w[5] = lda(tile, l15, r0,     4 + lg);
            w[6] = lda(tile, l15, r0 + 1, lg);
            w[7] = lda(tile, l15, r0 + 1, 4 + lg);
        }
    }

    // store: C row = word = lg*4 + j (verified layout)
    #pragma unroll
    for (int i = 0; i < NT; i++) {
        int col = (tbase + i) * 16 + l15;
        if (col < OUT_CH) {
            #pragma unroll
            for (int j = 0; j < 4; j++)
                out[(size_t)(block0 + lg * 4 + j) * D_OUT + D_WORDE + col] = mx[i][j];
        }
    }
}

// ---------- uniform 512-thread block: stage | bar | {6x tile-pair, 1x tile12, 1x emb}
__global__ void __launch_bounds__(512)
fused_kernel(const int* __restrict__ words, const int* __restrict__ chars,
             const float* __restrict__ W_word, const ushort* __restrict__ ws,
             float* __restrict__ out) {
    __shared__ __align__(16) ushort tile[TILE_U16];   // 32 KB

    const int tid  = threadIdx.x;
    const int lane = tid & 63;
    const int wave = tid >> 6;          // 0..7
    const int l15  = lane & 15;
    const int lg   = lane >> 4;

    const ushort* __restrict__ charP = ws;
    const ushort* __restrict__ WO    = ws + CHARP_U16;
    const int block0 = blockIdx.x * WPB;

    // ---- stage: every wave stages words {2w, 2w+1}; linear dest, swizzled source
    #pragma unroll
    for (int ww = 0; ww < 2; ww++) {
        const int wl = wave * 2 + ww;
        const int m  = block0 + wl;
        const int* __restrict__ cbase = chars + ((m & 63) * SENT + (m >> 6)) * WLEN;
        const int srcg = (lane & 7) ^ ((lane >> 3) & 7) ^ (wl & 7);
        #pragma unroll
        for (int s = 0; s < 2; s++) {
            const int idv = cbase[s * 8 + (lane >> 3)];
            GLOAD16(charP + idv * 64 + (srcg << 3), &tile[wl * 1024 + s * 512]);
        }
    }
    __syncthreads();                    // the only barrier; waves independent after

    if (wave < 6) {
        conv_ploop<2>(2 * wave, lane, l15, lg, tile, WO, out, block0);   // tiles 0..11
    } else if (wave == 6) {
        conv_ploop<1>(12, lane, l15, lg, tile, WO, out, block0);         // tile 12
    } else {
        // ---- emb wave: 16 rows, 4 in flight (proven r16/r18 pattern)
        const bool tail = lane < (75 - 64);
        #pragma unroll 1
        for (int r4 = 0; r4 < 4; r4++) {
            const int m0 = block0 + r4 * 4;
            float4v e0[4], e1[4];
            #pragma unroll
            for (int j = 0; j < 4; j++) {
                const float4v* __restrict__ src =
                    (const float4v*)(W_word + (size_t)words[m0 + j] * D_WORDE);
                e0[j] = src[lane];
                e1[j] = tail ? src[64 + lane] : (float4v){0, 0, 0, 0};
            }
            #pragma unroll
            for (int j = 0; j < 4; j++) {
                float4v* __restrict__ dst = (float4v*)(out + (size_t)(m0 + j) * D_OUT);
                dst[lane] = e0[j];
                if (tail) dst[64 + lane] = e1[j];
            }
        }
    }
}

// ---------- fallbacks (tiny ws): round-1 proven kernels ----------
__global__ void __launch_bounds__(256)
word_emb_kernel(const int* __restrict__ words, const float* __restrict__ W_word,
                float* __restrict__ out) {
    int wave = threadIdx.x >> 6, lane = threadIdx.x & 63;
    int m = blockIdx.x * 4 + wave;
    int idx = words[m];
    const float* __restrict__ src = W_word + (size_t)idx * D_WORDE;
    float* __restrict__ dst = out + (size_t)m * D_OUT;
    for (int j = lane; j < D_WORDE; j += 64) dst[j] = src[j];
}

__global__ void __launch_bounds__(256)
char_conv_f32_kernel(const int* __restrict__ chars, const float* __restrict__ W_char,
                     const float* __restrict__ conv_w, const float* __restrict__ conv_b,
                     float* __restrict__ out) {
    __shared__ __align__(16) float xs[D_CHARE * WLEN];
    __shared__ int ids[WLEN];
    int m = blockIdx.x, s = m >> 6, b = m & 63, tid = threadIdx.x;
    if (tid < WLEN) ids[tid] = chars[(b * SENT + s) * WLEN + tid];
    __syncthreads();
    for (int e = tid; e < D_CHARE * WLEN; e += 256) {
        int c = e >> 4, l = e & 15;
        xs[e] = W_char[ids[l] * D_CHARE + c];
    }
    __syncthreads();
    if (tid < OUT_CH) {
        float acc[NPOS];
        #pragma unroll
        for (int p = 0; p < NPOS; p++) acc[p] = 0.f;
        const float4* xs4 = (const float4*)xs;
        for (int c = 0; c < D_CHARE; c++) {
            float4 a0 = xs4[c*4+0], a1 = xs4[c*4+1], a2 = xs4[c*4+2], a3 = xs4[c*4+3];
            float xr[WLEN] = {a0.x,a0.y,a0.z,a0.w, a1.x,a1.y,a1.z,a1.w,
                              a2.x,a2.y,a2.z,a2.w, a3.x,a3.y,a3.z,a3.w};
            #pragma unroll
            for (int k = 0; k < KSIZE; k++) {
                float wv = conv_w[tid * (D_CHARE * KSIZE) + c * KSIZE + k];
                #pragma unroll
                for (int p = 0; p < NPOS; p++) acc[p] = fmaf(wv, xr[p + k], acc[p]);
            }
        }
        float mx = acc[0];
        #pragma unroll
        for (int p = 1; p < NPOS; p++) mx = fmaxf(mx, acc[p]);
        out[(size_t)m * D_OUT + D_WORDE + tid] = mx + conv_b[tid];
    }
}

extern "C" void kernel_launch(void* const* d_in, const int* in_sizes, int n_in,
                              void* d_out, int out_size, void* d_ws, size_t ws_size,
                              hipStream_t stream) {
    const int*   words  = (const int*)d_in[0];
    const int*   chars  = (const int*)d_in[1];
    const float* W_word = (const float*)d_in[2];
    const float* W_char = (const float*)d_in[3];
    const float* conv_w = (const float*)d_in[4];
    const float* conv_b = (const float*)d_in[5];
    float* out = (float*)d_out;

    if (ws_size >= WS_NEED) {
        ushort* ws = (ushort*)d_ws;
        hipLaunchKernelGGL(prep_kernel,
                           dim3((CHARP_U16 + WO_U16 + 255) / 256), dim3(256), 0, stream,
                           W_char, conv_w, conv_b, ws);
        hipLaunchKernelGGL(fused_kernel, dim3(CONV_BLOCKS), dim3(512), 0, stream,
                           words, chars, W_word, ws, out);
    } else {
        hipLaunchKernelGGL(word_emb_kernel, dim3(NWORDS / 4), dim3(256), 0, stream,
                           words, W_word, out);
        hipLaunchKernelGGL(char_conv_f32_kernel, dim3(NWORDS), dim3(256), 0, stream,
                           chars, W_char, conv_w, conv_b, out);
    }
}